// Round 17
// baseline (224.826 us; speedup 1.0000x reference)
//
#include <hip/hip_runtime.h>

typedef __attribute__((ext_vector_type(8))) __bf16 bf16x8;
typedef __attribute__((ext_vector_type(4))) __bf16 bf16x4;
typedef __attribute__((ext_vector_type(4))) float f32x4;
typedef __attribute__((ext_vector_type(16))) float f32x16;
typedef __attribute__((ext_vector_type(4))) unsigned uint32x4;
typedef __attribute__((ext_vector_type(2))) unsigned uint32x2;

#define AS1 __attribute__((address_space(1)))
#define AS3 __attribute__((address_space(3)))

#if __has_builtin(__builtin_amdgcn_exp2f)
#define EXP2(x) __builtin_amdgcn_exp2f(x)
#else
#define EXP2(x) exp2f(x)
#endif

#define QSCALE 0.18033688011112042f  // 0.125 * log2(e)

// ---------------- fused fp32 -> bf16 conversion (x, w_attn, w_proj) ----------------
#define N_X 4194304
#define N_WA 786432
#define N_WP 262144
__global__ __launch_bounds__(256) void convert_all_k(const float* __restrict__ x,
                                                     const float* __restrict__ wa,
                                                     const float* __restrict__ wp,
                                                     __bf16* __restrict__ xb,
                                                     __bf16* __restrict__ wab,
                                                     __bf16* __restrict__ wpb) {
  int i = (blockIdx.x * 256 + threadIdx.x) * 8;
  const float* src;
  __bf16* dst;
  int off;
  if (i < N_X)              { src = x;  dst = xb;  off = i; }
  else if (i < N_X + N_WA)  { src = wa; dst = wab; off = i - N_X; }
  else if (i < N_X + N_WA + N_WP) { src = wp; dst = wpb; off = i - N_X - N_WA; }
  else return;
  float4 v0 = *reinterpret_cast<const float4*>(src + off);
  float4 v1 = *reinterpret_cast<const float4*>(src + off + 4);
  bf16x8 o;
  o[0] = (__bf16)v0.x; o[1] = (__bf16)v0.y; o[2] = (__bf16)v0.z; o[3] = (__bf16)v0.w;
  o[4] = (__bf16)v1.x; o[5] = (__bf16)v1.y; o[6] = (__bf16)v1.z; o[7] = (__bf16)v1.w;
  *reinterpret_cast<bf16x8*>(dst + off) = o;
}

// ---------------- QKV GEMM: [M,1536] = x[M,512] @ w_attn^T + b ----------------
// 1D grid, XCD-chunked swizzle. BK=32, 3-slot depth-2 prefetch, counted vmcnt(4).
__global__ __launch_bounds__(256) void gemm_bt(const __bf16* __restrict__ A,
                                               const __bf16* __restrict__ Bm,
                                               const float* __restrict__ bias,
                                               void* __restrict__ outp,
                                               __bf16* __restrict__ vtout,
                                               int M, int N, int K) {
  __shared__ __bf16 smem[24576];  // slot s (0..2): A [s*8192, +4096), B [+4096, +4096)
  const int tid = threadIdx.x;
  const int lane = tid & 63;
  const int w = tid >> 6;
  const int wm = w >> 1, wn = w & 1;
  const int ll = lane & 15, lh = lane >> 4;  // lh = k-chunk (0..3)
  const int bid = (int)blockIdx.x;
  const int NT = N >> 7;
  const int xcd = bid & 7, lidx = bid >> 3;
  const int m0 = (xcd * 8 + lidx / NT) * 128;
  const int n0 = (lidx % NT) * 128;
  f32x4 acc[4][4] = {};

  auto stage = [&](int k0, int ss) {  // 4 loads/thread
    __bf16* al = smem + ss * 8192;
    __bf16* bl = al + 4096;
#pragma unroll
    for (int i = 0; i < 2; ++i) {
      int ch = i * 256 + tid;
      int r = ch >> 2, cs = (ch & 3) ^ ((r >> 1) & 3);  // pre-swizzled source chunk
      const __bf16* ga = A + (size_t)(m0 + r) * K + k0 + cs * 8;
      __builtin_amdgcn_global_load_lds((const AS1 void*)ga, (AS3 void*)(al + ch * 8), 16, 0, 0);
      const __bf16* gb = Bm + (size_t)(n0 + r) * K + k0 + cs * 8;
      __builtin_amdgcn_global_load_lds((const AS1 void*)gb, (AS3 void*)(bl + ch * 8), 16, 0, 0);
    }
  };

  const int nsteps = K >> 5;  // 16
  stage(0, 0);
  __builtin_amdgcn_sched_barrier(0);
  stage(32, 1);
  __builtin_amdgcn_sched_barrier(0);
  int slot = 0;
  for (int t = 0; t < nsteps; ++t) {
    // outstanding (oldest first): stage(t) [4] + stage(t+1) [4 if exists]
    if (t + 1 < nsteps) asm volatile("s_waitcnt vmcnt(4)" ::: "memory");
    else                asm volatile("s_waitcnt vmcnt(0)" ::: "memory");
    __builtin_amdgcn_sched_barrier(0);
    __builtin_amdgcn_s_barrier();  // all waves' stage(t) landed; slot (t+2)%3 free
    __builtin_amdgcn_sched_barrier(0);
    if (t + 2 < nsteps) {
      int s2 = slot + 2; if (s2 >= 3) s2 -= 3;
      stage((t + 2) << 5, s2);  // depth-2: 2 compute phases of latency cover
      __builtin_amdgcn_sched_barrier(0);
    }
    const __bf16* al = smem + slot * 8192;
    const __bf16* bl = al + 4096;
    bf16x8 af[4], bfr[4];
#pragma unroll
    for (int m = 0; m < 4; ++m) {
      int R = wm * 64 + m * 16 + ll;
      af[m] = *reinterpret_cast<const bf16x8*>(al + R * 32 + ((lh ^ ((R >> 1) & 3)) << 3));
    }
#pragma unroll
    for (int n = 0; n < 4; ++n) {
      int R = wn * 64 + n * 16 + ll;
      bfr[n] = *reinterpret_cast<const bf16x8*>(bl + R * 32 + ((lh ^ ((R >> 1) & 3)) << 3));
    }
    __builtin_amdgcn_s_setprio(1);
#pragma unroll
    for (int m = 0; m < 4; ++m)
#pragma unroll
      for (int n = 0; n < 4; ++n)
        acc[m][n] = __builtin_amdgcn_mfma_f32_16x16x32_bf16(af[m], bfr[n], acc[m][n], 0, 0, 0);
    __builtin_amdgcn_s_setprio(0);
    __builtin_amdgcn_sched_barrier(0);
    slot = (slot == 2) ? 0 : slot + 1;
  }
  if (n0 < 1024) {
    // Q/K region: per-wave LDS transpose -> coalesced bf16x8 stores
    __syncthreads();  // main-loop LDS reads by other waves must finish
    __bf16* tb = smem + w * 4096;  // 64x64 region/wave
    const float sc = (n0 < 512) ? (float)QSCALE : 1.0f;
#pragma unroll
    for (int m = 0; m < 4; ++m)
#pragma unroll
      for (int n = 0; n < 4; ++n) {
        float bs = bias[n0 + wn * 64 + n * 16 + ll];
#pragma unroll
        for (int r = 0; r < 4; ++r)
          tb[(m * 16 + lh * 4 + r) * 64 + n * 16 + ll] = (__bf16)((acc[m][n][r] + bs) * sc);
      }
    const int rsub = lane >> 3, csub = (lane & 7) * 8;
#pragma unroll
    for (int i = 0; i < 8; ++i) {
      bf16x8 vv = *reinterpret_cast<const bf16x8*>(tb + (i * 8 + rsub) * 64 + csub);
      *reinterpret_cast<bf16x8*>((__bf16*)outp +
          (size_t)(m0 + wm * 64 + i * 8 + rsub) * N + n0 + wn * 64 + csub) = vv;
    }
  } else {
    // V region -> vt transposed, via swizzled per-wave LDS transpose + coalesced stores.
    __syncthreads();  // main-loop LDS reads by other waves must finish
    __bf16* tb = smem + w * 4096;
#pragma unroll
    for (int m = 0; m < 4; ++m) {
      const int rb = m * 4 + lh;  // t-block index
#pragma unroll
      for (int n = 0; n < 4; ++n) {
        const int col = n * 16 + ll;  // d_local
        float bs = bias[n0 + wn * 64 + col];
        bf16x4 pk;
#pragma unroll
        for (int r = 0; r < 4; ++r) pk[r] = (__bf16)(acc[m][n][r] + bs);
        *reinterpret_cast<bf16x4*>(tb + col * 64 + ((rb ^ (col & 15)) << 2)) = pk;
      }
    }
    const int b = m0 >> 12;
    const int tbase = (m0 + wm * 64) & 4095;
    const int dbase = n0 - 1024 + wn * 64;
    const int dl = lane >> 3;           // 0..7
    const int j1 = (lane & 7) * 2;      // t-block pair
    const int tloc = (lane & 7) * 8;
#pragma unroll
    for (int i = 0; i < 8; ++i) {
      const int col = i * 8 + dl;
      uint32x2 lo = *reinterpret_cast<const uint32x2*>(tb + col * 64 + ((j1 ^ (col & 15)) << 2));
      uint32x2 hi = *reinterpret_cast<const uint32x2*>(tb + col * 64 + (((j1 + 1) ^ (col & 15)) << 2));
      uint32x4 full = {lo[0], lo[1], hi[0], hi[1]};
      *reinterpret_cast<uint32x4*>(vtout + ((size_t)(b * 512 + dbase + col)) * 4096 + tbase + tloc) = full;
    }
  }
}

// ---------------- proj GEMM: out[8192,512] = y[8192,512] @ wp^T + b (fp32 out) ----------------
// 64x64 tiles -> 1024 blocks = 4 blocks/CU. 3-slot depth-2, counted vmcnt(2).
__global__ __launch_bounds__(256) void gemm2_k(const __bf16* __restrict__ A,
                                               const __bf16* __restrict__ Bm,
                                               const float* __restrict__ bias,
                                               float* __restrict__ out) {
  __shared__ __bf16 smem[12288];  // slot s (0..2): A [s*4096, +2048), B [+2048, +2048)
  const int K = 512, N = 512;
  const int tid = threadIdx.x, lane = tid & 63, w = tid >> 6;
  const int wm = w >> 1, wn = w & 1;
  const int ll = lane & 15, lh = lane >> 4;
  const int bid = (int)blockIdx.x;  // 1024
  const int xcd = bid & 7, lidx = bid >> 3;
  const int m0 = (xcd * 16 + (lidx >> 3)) * 64;
  const int n0 = (lidx & 7) * 64;
  f32x4 acc[2][2] = {};

  const int r = tid >> 2, cs = (tid & 3) ^ ((r >> 1) & 3);
  const __bf16* ga = A + (size_t)(m0 + r) * K + cs * 8;
  const __bf16* gb = Bm + (size_t)(n0 + r) * K + cs * 8;

  auto stage = [&](int k0, int ss) {  // 2 loads/thread
    __bf16* al = smem + ss * 4096;
    __builtin_amdgcn_global_load_lds((const AS1 void*)(ga + k0), (AS3 void*)(al + tid * 8), 16, 0, 0);
    __builtin_amdgcn_global_load_lds((const AS1 void*)(gb + k0), (AS3 void*)(al + 2048 + tid * 8), 16, 0, 0);
  };

  stage(0, 0);
  __builtin_amdgcn_sched_barrier(0);
  stage(32, 1);
  __builtin_amdgcn_sched_barrier(0);
  int slot = 0;
  for (int t = 0; t < 16; ++t) {
    if (t + 1 < 16) asm volatile("s_waitcnt vmcnt(2)" ::: "memory");
    else            asm volatile("s_waitcnt vmcnt(0)" ::: "memory");
    __builtin_amdgcn_sched_barrier(0);
    __builtin_amdgcn_s_barrier();
    __builtin_amdgcn_sched_barrier(0);
    if (t + 2 < 16) {
      int s2 = slot + 2; if (s2 >= 3) s2 -= 3;
      stage((t + 2) << 5, s2);
      __builtin_amdgcn_sched_barrier(0);
    }
    const __bf16* al = smem + slot * 4096;
    const __bf16* bl = al + 2048;
    bf16x8 af[2], bfr[2];
#pragma unroll
    for (int m = 0; m < 2; ++m) {
      int R = wm * 32 + m * 16 + ll;
      af[m] = *reinterpret_cast<const bf16x8*>(al + R * 32 + ((lh ^ ((R >> 1) & 3)) << 3));
    }
#pragma unroll
    for (int n = 0; n < 2; ++n) {
      int R = wn * 32 + n * 16 + ll;
      bfr[n] = *reinterpret_cast<const bf16x8*>(bl + R * 32 + ((lh ^ ((R >> 1) & 3)) << 3));
    }
    __builtin_amdgcn_s_setprio(1);
#pragma unroll
    for (int m = 0; m < 2; ++m)
#pragma unroll
      for (int n = 0; n < 2; ++n)
        acc[m][n] = __builtin_amdgcn_mfma_f32_16x16x32_bf16(af[m], bfr[n], acc[m][n], 0, 0, 0);
    __builtin_amdgcn_s_setprio(0);
    __builtin_amdgcn_sched_barrier(0);
    slot = (slot == 2) ? 0 : slot + 1;
  }
#pragma unroll
  for (int m = 0; m < 2; ++m) {
    int gm = m0 + wm * 32 + m * 16 + lh * 4;
#pragma unroll
    for (int n = 0; n < 2; ++n) {
      int gn = n0 + wn * 32 + n * 16 + ll;
      float bs = bias[gn];
#pragma unroll
      for (int r4 = 0; r4 < 4; ++r4)
        out[(size_t)(gm + r4) * N + gn] = acc[m][n][r4] + bs;
    }
  }
}

// ---------------- chunk table: 12-tile chunks, sorted heavy-first ----------------
struct Tbl { unsigned short t[204]; };
constexpr Tbl build_tbl() {
  Tbl T{};
  int sizes[204] = {};
  int n = 0;
  for (int p = 0; p < 2; ++p)
    for (int qx = 0; qx < 32; ++qx) {
      int total = 2 * qx + 2;
      int nch = (total + 11) / 12;
      int cum = 0;
      for (int q = 0; q < qx; ++q) cum += (2 * q + 13) / 12;
      for (int c = 0; c < nch; ++c) {
        int sz = total - 12 * c; if (sz > 12) sz = 12;
        T.t[n] = (unsigned short)(qx | (c << 5) | (p << 8) | ((cum + c) << 9));
        sizes[n] = sz;
        ++n;
      }
    }
  for (int i = 1; i < n; ++i) {  // stable insertion sort, size desc
    unsigned short tv = T.t[i]; int sv = sizes[i];
    int j = i - 1;
    while (j >= 0 && sizes[j] < sv) { T.t[j + 1] = T.t[j]; sizes[j + 1] = sizes[j]; --j; }
    T.t[j + 1] = tv; sizes[j + 1] = sv;
  }
  return T;
}
__device__ __constant__ Tbl g_tbl = build_tbl();

// ---------------- causal flash attention, split-KV chunks, fixed-base softmax ----------------
// K depth-2 prefetch (3 slots) + V depth-1 (2 slots) = 40KB LDS -> 4 blocks/CU.
// Combine fused via last-finisher atomic: the final chunk of each q-block sums partials
// (overlaps combine with the attn tail; removes the separate kernel + launch gap).
__device__ inline unsigned cvtpk(float lo, float hi_) {
  unsigned r;
  asm("v_cvt_pk_bf16_f32 %0, %1, %2" : "=v"(r) : "v"(lo), "v"(hi_));
  return r;
}

__global__ __launch_bounds__(256, 4) void attn_k(const __bf16* __restrict__ qkv,
                                                 const __bf16* __restrict__ vt,
                                                 __bf16* __restrict__ opart,
                                                 float* __restrict__ lpart,
                                                 unsigned* __restrict__ counters,
                                                 __bf16* __restrict__ y) {
  __shared__ __bf16 k_lds[3][64 * 64];  // 24 KB
  __shared__ __bf16 v_lds[2][64 * 64];  // 16 KB  (total exactly 40KB: 4 blocks/CU)
  const int tid = threadIdx.x, lane = tid & 63, w = tid >> 6;
  const int hi = lane >> 5, q31 = lane & 31;
  const int swz = q31 & 7;

  const int bid = (int)blockIdx.x;  // 1632
  const int e = g_tbl.t[bid >> 3];
  const int qx = e & 31, c = (e >> 5) & 7, p = (e >> 8) & 1, j = e >> 9;
  const int bh = (bid & 7) * 2 + p;  // XCD-local heads
  const int pslot = bh * 102 + j;
  const int b = bh >> 3, h = bh & 7;
  const int q0 = qx * 128;
  const int qw0 = q0 + w * 32;
  const int t0 = 12 * c;
  const int t1 = min(12 * c + 12, 2 * qx + 2);  // always >= 2 tiles

  const __bf16* qp = qkv + (size_t)b * 4096 * 1536 + h * 64;
  const __bf16* vtp = vt + (size_t)(b * 512 + h * 64) * 4096;

  // per-lane incremental stage pointers (involution XOR pre-applied to source)
  const int rr = tid >> 3;               // row within half-tile (0..31)
  const int cs = (tid & 7) ^ (rr & 7);   // (rr+32)&7 == rr&7, so same XOR both halves
  const __bf16* kg = qp + 512 + (size_t)(t0 * 64 + rr) * 1536 + cs * 8;
  const __bf16* vg = vtp + (size_t)rr * 4096 + t0 * 64 + cs * 8;

  bf16x8 qf[4];
  {
    const __bf16* qr = qp + (size_t)(qw0 + q31) * 1536 + hi * 8;
#pragma unroll
    for (int d = 0; d < 4; ++d) qf[d] = *reinterpret_cast<const bf16x8*>(qr + d * 16);
  }

  f32x16 o0 = {}, o1 = {};
  float l_run = 0.f;

  auto stageK = [&](int ks) {  // 2 loads/thread
    __builtin_amdgcn_global_load_lds((const AS1 void*)kg,
        (AS3 void*)(&k_lds[ks][w * 512]), 16, 0, 0);
    __builtin_amdgcn_global_load_lds((const AS1 void*)(kg + 32 * 1536),
        (AS3 void*)(&k_lds[ks][2048 + w * 512]), 16, 0, 0);
    kg += 64 * 1536;
  };
  auto stageV = [&](int vs) {  // 2 loads/thread
    __builtin_amdgcn_global_load_lds((const AS1 void*)vg,
        (AS3 void*)(&v_lds[vs][w * 512]), 16, 0, 0);
    __builtin_amdgcn_global_load_lds((const AS1 void*)(vg + 32 * 4096),
        (AS3 void*)(&v_lds[vs][2048 + w * 512]), 16, 0, 0);
    vg += 64;
  };

  // prologue
  stageV(0);
  __builtin_amdgcn_sched_barrier(0);
  stageK(0);
  __builtin_amdgcn_sched_barrier(0);
  stageK(1);
  __builtin_amdgcn_sched_barrier(0);

  int kslot = 0, vslot = 0;
  for (int t = t0; t < t1; ++t) {
    if (t + 1 < t1) asm volatile("s_waitcnt vmcnt(2)" ::: "memory");
    else            asm volatile("s_waitcnt vmcnt(0)" ::: "memory");
    __builtin_amdgcn_sched_barrier(0);
    __builtin_amdgcn_s_barrier();  // all waves' tile-t data landed
    __builtin_amdgcn_sched_barrier(0);
    if (t + 1 < t1) {
      stageV(vslot ^ 1);           // V depth-1
      __builtin_amdgcn_sched_barrier(0);
      if (t + 2 < t1) {
        int k2 = kslot + 2; if (k2 >= 3) k2 -= 3;
        stageK(k2);                // K depth-2
        __builtin_amdgcn_sched_barrier(0);
      }
    }
    const int kv0 = t * 64;
    if (kv0 <= qw0 + 31) {
      // S^T = K . Q^T
      f32x16 s0 = {}, s1 = {};
      __builtin_amdgcn_s_setprio(1);
#pragma unroll
      for (int d = 0; d < 4; ++d) {
        int c0 = ((d * 2 + hi) ^ swz) * 8;
        s0 = __builtin_amdgcn_mfma_f32_32x32x16_bf16(
            *reinterpret_cast<const bf16x8*>(&k_lds[kslot][q31 * 64 + c0]), qf[d], s0, 0, 0, 0);
        s1 = __builtin_amdgcn_mfma_f32_32x32x16_bf16(
            *reinterpret_cast<const bf16x8*>(&k_lds[kslot][(32 + q31) * 64 + c0]), qf[d], s1, 0, 0, 0);
      }
      __builtin_amdgcn_s_setprio(0);
      if (kv0 + 63 > qw0) {  // diagonal tile for this wave
        const int q = qw0 + q31;
#pragma unroll
        for (int r = 0; r < 16; ++r) {
          int crow = (r & 3) + 8 * (r >> 2) + 4 * hi;
          if (kv0 + crow > q) s0[r] = -1e30f;
          if (kv0 + 32 + crow > q) s1[r] = -1e30f;
        }
      }
      // fixed-base softmax: p = exp2(s); base shift cancels in O/l
#pragma unroll
      for (int r = 0; r < 16; ++r) s0[r] = EXP2(s0[r]);
#pragma unroll
      for (int r = 0; r < 16; ++r) s1[r] = EXP2(s1[r]);
      // lane-local tree sum (cross-lane merge deferred to chunk end)
      {
        float a8[8];
#pragma unroll
        for (int r = 0; r < 8; ++r)
          a8[r] = (s0[r] + s0[r + 8]) + (s1[r] + s1[r + 8]);
        l_run += (((a8[0] + a8[1]) + (a8[2] + a8[3])) + ((a8[4] + a8[5]) + (a8[6] + a8[7])));
      }
      // P fragments: cvt_pk + permlane32_swap
      uint32x4 pa[4];
#pragma unroll
      for (int half = 0; half < 2; ++half) {
        const int bse = half * 8;
        {
          unsigned x1 = cvtpk(s0[bse + 0], s0[bse + 1]);
          unsigned y1 = cvtpk(s0[bse + 4], s0[bse + 5]);
          asm("v_permlane32_swap_b32 %0, %1" : "+v"(x1), "+v"(y1));
          pa[half][0] = x1; pa[half][2] = y1;
          unsigned x2 = cvtpk(s0[bse + 2], s0[bse + 3]);
          unsigned y2 = cvtpk(s0[bse + 6], s0[bse + 7]);
          asm("v_permlane32_swap_b32 %0, %1" : "+v"(x2), "+v"(y2));
          pa[half][1] = x2; pa[half][3] = y2;
        }
        {
          unsigned x1 = cvtpk(s1[bse + 0], s1[bse + 1]);
          unsigned y1 = cvtpk(s1[bse + 4], s1[bse + 5]);
          asm("v_permlane32_swap_b32 %0, %1" : "+v"(x1), "+v"(y1));
          pa[2 + half][0] = x1; pa[2 + half][2] = y1;
          unsigned x2 = cvtpk(s1[bse + 2], s1[bse + 3]);
          unsigned y2 = cvtpk(s1[bse + 6], s1[bse + 7]);
          asm("v_permlane32_swap_b32 %0, %1" : "+v"(x2), "+v"(y2));
          pa[2 + half][1] = x2; pa[2 + half][3] = y2;
        }
      }
      // O^T += V^T . P^T
      __builtin_amdgcn_s_setprio(1);
#pragma unroll
      for (int ks = 0; ks < 4; ++ks) {
        int c0 = ((ks * 2 + hi) ^ swz) * 8;
        bf16x8 pfrag = __builtin_bit_cast(bf16x8, pa[ks]);
        o0 = __builtin_amdgcn_mfma_f32_32x32x16_bf16(
            *reinterpret_cast<const bf16x8*>(&v_lds[vslot][q31 * 64 + c0]), pfrag, o0, 0, 0, 0);
        o1 = __builtin_amdgcn_mfma_f32_32x32x16_bf16(
            *reinterpret_cast<const bf16x8*>(&v_lds[vslot][(32 + q31) * 64 + c0]), pfrag, o1, 0, 0, 0);
      }
      __builtin_amdgcn_s_setprio(0);
    }
    __builtin_amdgcn_sched_barrier(0);
    kslot = (kslot == 2) ? 0 : kslot + 1;
    vslot ^= 1;
  }

  // merge lane halves once per chunk
  l_run += __shfl_xor(l_run, 32);

  // epilogue
  const int rloc = w * 32 + q31;
  if (t0 == 0 && t1 == 2 * qx + 2) {
    // single-chunk q-block: write normalized y directly, no combine needed
    const float inv = 1.f / l_run;
    __bf16* yr = y + ((size_t)b * 4096 + qw0 + q31) * 512 + h * 64;
#pragma unroll
    for (int g = 0; g < 4; ++g) {
      bf16x4 v0, v1;
#pragma unroll
      for (int jj = 0; jj < 4; ++jj) {
        v0[jj] = (__bf16)(o0[g * 4 + jj] * inv);
        v1[jj] = (__bf16)(o1[g * 4 + jj] * inv);
      }
      *reinterpret_cast<bf16x4*>(yr + 8 * g + 4 * hi) = v0;
      *reinterpret_cast<bf16x4*>(yr + 32 + 8 * g + 4 * hi) = v1;
    }
  } else {
    // multi-chunk: store RAW partial (shared fixed base) + l
    __bf16* ob = opart + ((size_t)pslot * 128 + rloc) * 64;
#pragma unroll
    for (int g = 0; g < 4; ++g) {
      bf16x4 v0, v1;
#pragma unroll
      for (int jj = 0; jj < 4; ++jj) {
        v0[jj] = (__bf16)(o0[g * 4 + jj]);
        v1[jj] = (__bf16)(o1[g * 4 + jj]);
      }
      *reinterpret_cast<bf16x4*>(ob + 8 * g + 4 * hi) = v0;
      *reinterpret_cast<bf16x4*>(ob + 32 + 8 * g + 4 * hi) = v1;
    }
    if (hi == 0) lpart[pslot * 128 + rloc] = l_run;

    // ---- last-finisher combine (deterministic: fixed i-order sum) ----
    const int nch = (2 * qx + 13) / 12;
    const int g0 = pslot - c;  // first partial slot of this q-block
    __syncthreads();  // all this block's partial stores drained (vmcnt 0)
    int* flag = (int*)&k_lds[0][0];  // reuse LDS (main loop done)
    if (tid == 0) {
      __threadfence();  // agent-scope release: partials visible device-wide
      *flag = (int)atomicAdd(&counters[bh * 26 + (qx - 6)], 1u);
    }
    __syncthreads();
    if (*flag == nch - 1) {
      __threadfence();  // acquire: see all other chunks' partials
      const int r = tid >> 1, dh = (tid & 1) * 32;
      float W = 0.f;
      float acc[32] = {};
      for (int i = 0; i < nch; ++i) {
        W += lpart[(g0 + i) * 128 + r];
        const __bf16* op = opart + ((size_t)(g0 + i) * 128 + r) * 64 + dh;
#pragma unroll
        for (int jj = 0; jj < 4; ++jj) {
          bf16x8 v = *reinterpret_cast<const bf16x8*>(op + jj * 8);
#pragma unroll
          for (int ee = 0; ee < 8; ++ee) acc[jj * 8 + ee] += (float)v[ee];
        }
      }
      const float inv = 1.f / W;
      __bf16* yr = y + ((size_t)b * 4096 + qx * 128 + r) * 512 + h * 64 + dh;
#pragma unroll
      for (int jj = 0; jj < 4; ++jj) {
        bf16x8 ov;
#pragma unroll
        for (int ee = 0; ee < 8; ++ee) ov[ee] = (__bf16)(acc[jj * 8 + ee] * inv);
        *reinterpret_cast<bf16x8*>(yr + jj * 8) = ov;
      }
    }
  }
}

// ---------------- launcher ----------------
extern "C" void kernel_launch(void* const* d_in, const int* in_sizes, int n_in,
                              void* d_out, int out_size, void* d_ws, size_t ws_size,
                              hipStream_t stream) {
  const float* x      = (const float*)d_in[0];
  const float* w_attn = (const float*)d_in[1];
  const float* b_attn = (const float*)d_in[2];
  const float* w_proj = (const float*)d_in[3];
  const float* b_proj = (const float*)d_in[4];
  float* out = (float*)d_out;

  const int Bv = 2, T = 4096, C = 512;
  const int M = Bv * T;  // 8192

  // ws layout (elements); opart aliases x_bf (x dead after gemm1, stream-ordered)
  const size_t NPART = (size_t)1632 * 128 * 64;
  __bf16* opart  = (__bf16*)d_ws;
  __bf16* x_bf   = opart;                            // 4,194,304 (subset)
  __bf16* wa_bf  = opart + NPART;                    // 786,432
  __bf16* wp_bf  = wa_bf + (size_t)786432;           // 262,144
  __bf16* qkv_bf = wp_bf + (size_t)262144;           // 12,582,912
  __bf16* y_bf   = qkv_bf + (size_t)12582912;        // 4,194,304
  __bf16* vt_bf  = y_bf + (size_t)4194304;           // 4,194,304
  float*  lpart  = (float*)(vt_bf + (size_t)4194304);  // 208,896 f32
  unsigned* counters = (unsigned*)(lpart + 208896);    // 416 u32

  hipMemsetAsync(counters, 0, 416 * sizeof(unsigned), stream);

  const int ntot = N_X + N_WA + N_WP;
  convert_all_k<<<(ntot / 8 + 255) / 256, 256, 0, stream>>>(x, w_attn, w_proj, x_bf, wa_bf, wp_bf);

  gemm_bt<<<dim3((3 * C / 128) * (M / 128)), 256, 0, stream>>>(x_bf, wa_bf, b_attn, qkv_bf, vt_bf, M, 3 * C, C);
  attn_k<<<dim3(1632), 256, 0, stream>>>(qkv_bf, vt_bf, opart, lpart, counters, y_bf);
  gemm2_k<<<dim3(1024), 256, 0, stream>>>(y_bf, wp_bf, b_proj, out);
}

// Round 18
// 97.299 us; speedup vs baseline: 2.3107x; 2.3107x over previous
//
#include <hip/hip_runtime.h>

typedef __attribute__((ext_vector_type(8))) __bf16 bf16x8;
typedef __attribute__((ext_vector_type(4))) __bf16 bf16x4;
typedef __attribute__((ext_vector_type(4))) float f32x4;
typedef __attribute__((ext_vector_type(16))) float f32x16;
typedef __attribute__((ext_vector_type(4))) unsigned uint32x4;
typedef __attribute__((ext_vector_type(2))) unsigned uint32x2;

#define AS1 __attribute__((address_space(1)))
#define AS3 __attribute__((address_space(3)))

#if __has_builtin(__builtin_amdgcn_exp2f)
#define EXP2(x) __builtin_amdgcn_exp2f(x)
#else
#define EXP2(x) exp2f(x)
#endif

#define QSCALE 0.18033688011112042f  // 0.125 * log2(e)

// ---------------- fused fp32 -> bf16 conversion (x, w_attn, w_proj) ----------------
#define N_X 4194304
#define N_WA 786432
#define N_WP 262144
__global__ __launch_bounds__(256) void convert_all_k(const float* __restrict__ x,
                                                     const float* __restrict__ wa,
                                                     const float* __restrict__ wp,
                                                     __bf16* __restrict__ xb,
                                                     __bf16* __restrict__ wab,
                                                     __bf16* __restrict__ wpb) {
  int i = (blockIdx.x * 256 + threadIdx.x) * 8;
  const float* src;
  __bf16* dst;
  int off;
  if (i < N_X)              { src = x;  dst = xb;  off = i; }
  else if (i < N_X + N_WA)  { src = wa; dst = wab; off = i - N_X; }
  else if (i < N_X + N_WA + N_WP) { src = wp; dst = wpb; off = i - N_X - N_WA; }
  else return;
  float4 v0 = *reinterpret_cast<const float4*>(src + off);
  float4 v1 = *reinterpret_cast<const float4*>(src + off + 4);
  bf16x8 o;
  o[0] = (__bf16)v0.x; o[1] = (__bf16)v0.y; o[2] = (__bf16)v0.z; o[3] = (__bf16)v0.w;
  o[4] = (__bf16)v1.x; o[5] = (__bf16)v1.y; o[6] = (__bf16)v1.z; o[7] = (__bf16)v1.w;
  *reinterpret_cast<bf16x8*>(dst + off) = o;
}

// ---------------- QKV GEMM: [M,1536] = x[M,512] @ w_attn^T + b ----------------
// 1D grid, XCD-chunked swizzle. BK=32, 3-slot depth-2 prefetch, counted vmcnt(4).
__global__ __launch_bounds__(256) void gemm_bt(const __bf16* __restrict__ A,
                                               const __bf16* __restrict__ Bm,
                                               const float* __restrict__ bias,
                                               void* __restrict__ outp,
                                               __bf16* __restrict__ vtout,
                                               int M, int N, int K) {
  __shared__ __bf16 smem[24576];  // slot s (0..2): A [s*8192, +4096), B [+4096, +4096)
  const int tid = threadIdx.x;
  const int lane = tid & 63;
  const int w = tid >> 6;
  const int wm = w >> 1, wn = w & 1;
  const int ll = lane & 15, lh = lane >> 4;  // lh = k-chunk (0..3)
  const int bid = (int)blockIdx.x;
  const int NT = N >> 7;
  const int xcd = bid & 7, lidx = bid >> 3;
  const int m0 = (xcd * 8 + lidx / NT) * 128;
  const int n0 = (lidx % NT) * 128;
  f32x4 acc[4][4] = {};

  auto stage = [&](int k0, int ss) {  // 4 loads/thread
    __bf16* al = smem + ss * 8192;
    __bf16* bl = al + 4096;
#pragma unroll
    for (int i = 0; i < 2; ++i) {
      int ch = i * 256 + tid;
      int r = ch >> 2, cs = (ch & 3) ^ ((r >> 1) & 3);  // pre-swizzled source chunk
      const __bf16* ga = A + (size_t)(m0 + r) * K + k0 + cs * 8;
      __builtin_amdgcn_global_load_lds((const AS1 void*)ga, (AS3 void*)(al + ch * 8), 16, 0, 0);
      const __bf16* gb = Bm + (size_t)(n0 + r) * K + k0 + cs * 8;
      __builtin_amdgcn_global_load_lds((const AS1 void*)gb, (AS3 void*)(bl + ch * 8), 16, 0, 0);
    }
  };

  const int nsteps = K >> 5;  // 16
  stage(0, 0);
  __builtin_amdgcn_sched_barrier(0);
  stage(32, 1);
  __builtin_amdgcn_sched_barrier(0);
  int slot = 0;
  for (int t = 0; t < nsteps; ++t) {
    // outstanding (oldest first): stage(t) [4] + stage(t+1) [4 if exists]
    if (t + 1 < nsteps) asm volatile("s_waitcnt vmcnt(4)" ::: "memory");
    else                asm volatile("s_waitcnt vmcnt(0)" ::: "memory");
    __builtin_amdgcn_sched_barrier(0);
    __builtin_amdgcn_s_barrier();  // all waves' stage(t) landed; slot (t+2)%3 free
    __builtin_amdgcn_sched_barrier(0);
    if (t + 2 < nsteps) {
      int s2 = slot + 2; if (s2 >= 3) s2 -= 3;
      stage((t + 2) << 5, s2);  // depth-2: 2 compute phases of latency cover
      __builtin_amdgcn_sched_barrier(0);
    }
    const __bf16* al = smem + slot * 8192;
    const __bf16* bl = al + 4096;
    bf16x8 af[4], bfr[4];
#pragma unroll
    for (int m = 0; m < 4; ++m) {
      int R = wm * 64 + m * 16 + ll;
      af[m] = *reinterpret_cast<const bf16x8*>(al + R * 32 + ((lh ^ ((R >> 1) & 3)) << 3));
    }
#pragma unroll
    for (int n = 0; n < 4; ++n) {
      int R = wn * 64 + n * 16 + ll;
      bfr[n] = *reinterpret_cast<const bf16x8*>(bl + R * 32 + ((lh ^ ((R >> 1) & 3)) << 3));
    }
    __builtin_amdgcn_s_setprio(1);
#pragma unroll
    for (int m = 0; m < 4; ++m)
#pragma unroll
      for (int n = 0; n < 4; ++n)
        acc[m][n] = __builtin_amdgcn_mfma_f32_16x16x32_bf16(af[m], bfr[n], acc[m][n], 0, 0, 0);
    __builtin_amdgcn_s_setprio(0);
    __builtin_amdgcn_sched_barrier(0);
    slot = (slot == 2) ? 0 : slot + 1;
  }
  if (n0 < 1024) {
    // Q/K region: per-wave LDS transpose -> coalesced bf16x8 stores
    __syncthreads();  // main-loop LDS reads by other waves must finish
    __bf16* tb = smem + w * 4096;  // 64x64 region/wave
    const float sc = (n0 < 512) ? (float)QSCALE : 1.0f;
#pragma unroll
    for (int m = 0; m < 4; ++m)
#pragma unroll
      for (int n = 0; n < 4; ++n) {
        float bs = bias[n0 + wn * 64 + n * 16 + ll];
#pragma unroll
        for (int r = 0; r < 4; ++r)
          tb[(m * 16 + lh * 4 + r) * 64 + n * 16 + ll] = (__bf16)((acc[m][n][r] + bs) * sc);
      }
    const int rsub = lane >> 3, csub = (lane & 7) * 8;
#pragma unroll
    for (int i = 0; i < 8; ++i) {
      bf16x8 vv = *reinterpret_cast<const bf16x8*>(tb + (i * 8 + rsub) * 64 + csub);
      *reinterpret_cast<bf16x8*>((__bf16*)outp +
          (size_t)(m0 + wm * 64 + i * 8 + rsub) * N + n0 + wn * 64 + csub) = vv;
    }
  } else {
    // V region -> vt transposed, via swizzled per-wave LDS transpose + coalesced stores.
    __syncthreads();  // main-loop LDS reads by other waves must finish
    __bf16* tb = smem + w * 4096;
#pragma unroll
    for (int m = 0; m < 4; ++m) {
      const int rb = m * 4 + lh;  // t-block index
#pragma unroll
      for (int n = 0; n < 4; ++n) {
        const int col = n * 16 + ll;  // d_local
        float bs = bias[n0 + wn * 64 + col];
        bf16x4 pk;
#pragma unroll
        for (int r = 0; r < 4; ++r) pk[r] = (__bf16)(acc[m][n][r] + bs);
        *reinterpret_cast<bf16x4*>(tb + col * 64 + ((rb ^ (col & 15)) << 2)) = pk;
      }
    }
    const int b = m0 >> 12;
    const int tbase = (m0 + wm * 64) & 4095;
    const int dbase = n0 - 1024 + wn * 64;
    const int dl = lane >> 3;           // 0..7
    const int j1 = (lane & 7) * 2;      // t-block pair
    const int tloc = (lane & 7) * 8;
#pragma unroll
    for (int i = 0; i < 8; ++i) {
      const int col = i * 8 + dl;
      uint32x2 lo = *reinterpret_cast<const uint32x2*>(tb + col * 64 + ((j1 ^ (col & 15)) << 2));
      uint32x2 hi = *reinterpret_cast<const uint32x2*>(tb + col * 64 + (((j1 + 1) ^ (col & 15)) << 2));
      uint32x4 full = {lo[0], lo[1], hi[0], hi[1]};
      *reinterpret_cast<uint32x4*>(vtout + ((size_t)(b * 512 + dbase + col)) * 4096 + tbase + tloc) = full;
    }
  }
}

// ---------------- proj GEMM: out[8192,512] = y[8192,512] @ wp^T + b (fp32 out) ----------------
// 64x64 tiles -> 1024 blocks = 4 blocks/CU. 3-slot depth-2, counted vmcnt(2).
__global__ __launch_bounds__(256) void gemm2_k(const __bf16* __restrict__ A,
                                               const __bf16* __restrict__ Bm,
                                               const float* __restrict__ bias,
                                               float* __restrict__ out) {
  __shared__ __bf16 smem[12288];  // slot s (0..2): A [s*4096, +2048), B [+2048, +2048)
  const int K = 512, N = 512;
  const int tid = threadIdx.x, lane = tid & 63, w = tid >> 6;
  const int wm = w >> 1, wn = w & 1;
  const int ll = lane & 15, lh = lane >> 4;
  const int bid = (int)blockIdx.x;  // 1024
  const int xcd = bid & 7, lidx = bid >> 3;
  const int m0 = (xcd * 16 + (lidx >> 3)) * 64;
  const int n0 = (lidx & 7) * 64;
  f32x4 acc[2][2] = {};

  const int r = tid >> 2, cs = (tid & 3) ^ ((r >> 1) & 3);
  const __bf16* ga = A + (size_t)(m0 + r) * K + cs * 8;
  const __bf16* gb = Bm + (size_t)(n0 + r) * K + cs * 8;

  auto stage = [&](int k0, int ss) {  // 2 loads/thread
    __bf16* al = smem + ss * 4096;
    __builtin_amdgcn_global_load_lds((const AS1 void*)(ga + k0), (AS3 void*)(al + tid * 8), 16, 0, 0);
    __builtin_amdgcn_global_load_lds((const AS1 void*)(gb + k0), (AS3 void*)(al + 2048 + tid * 8), 16, 0, 0);
  };

  stage(0, 0);
  __builtin_amdgcn_sched_barrier(0);
  stage(32, 1);
  __builtin_amdgcn_sched_barrier(0);
  int slot = 0;
  for (int t = 0; t < 16; ++t) {
    if (t + 1 < 16) asm volatile("s_waitcnt vmcnt(2)" ::: "memory");
    else            asm volatile("s_waitcnt vmcnt(0)" ::: "memory");
    __builtin_amdgcn_sched_barrier(0);
    __builtin_amdgcn_s_barrier();
    __builtin_amdgcn_sched_barrier(0);
    if (t + 2 < 16) {
      int s2 = slot + 2; if (s2 >= 3) s2 -= 3;
      stage((t + 2) << 5, s2);
      __builtin_amdgcn_sched_barrier(0);
    }
    const __bf16* al = smem + slot * 4096;
    const __bf16* bl = al + 2048;
    bf16x8 af[2], bfr[2];
#pragma unroll
    for (int m = 0; m < 2; ++m) {
      int R = wm * 32 + m * 16 + ll;
      af[m] = *reinterpret_cast<const bf16x8*>(al + R * 32 + ((lh ^ ((R >> 1) & 3)) << 3));
    }
#pragma unroll
    for (int n = 0; n < 2; ++n) {
      int R = wn * 32 + n * 16 + ll;
      bfr[n] = *reinterpret_cast<const bf16x8*>(bl + R * 32 + ((lh ^ ((R >> 1) & 3)) << 3));
    }
    __builtin_amdgcn_s_setprio(1);
#pragma unroll
    for (int m = 0; m < 2; ++m)
#pragma unroll
      for (int n = 0; n < 2; ++n)
        acc[m][n] = __builtin_amdgcn_mfma_f32_16x16x32_bf16(af[m], bfr[n], acc[m][n], 0, 0, 0);
    __builtin_amdgcn_s_setprio(0);
    __builtin_amdgcn_sched_barrier(0);
    slot = (slot == 2) ? 0 : slot + 1;
  }
#pragma unroll
  for (int m = 0; m < 2; ++m) {
    int gm = m0 + wm * 32 + m * 16 + lh * 4;
#pragma unroll
    for (int n = 0; n < 2; ++n) {
      int gn = n0 + wn * 32 + n * 16 + ll;
      float bs = bias[gn];
#pragma unroll
      for (int r4 = 0; r4 < 4; ++r4)
        out[(size_t)(gm + r4) * N + gn] = acc[m][n][r4] + bs;
    }
  }
}

// ---------------- chunk table: 12-tile chunks, sorted heavy-first ----------------
struct Tbl { unsigned short t[204]; };
constexpr Tbl build_tbl() {
  Tbl T{};
  int sizes[204] = {};
  int n = 0;
  for (int p = 0; p < 2; ++p)
    for (int qx = 0; qx < 32; ++qx) {
      int total = 2 * qx + 2;
      int nch = (total + 11) / 12;
      int cum = 0;
      for (int q = 0; q < qx; ++q) cum += (2 * q + 13) / 12;
      for (int c = 0; c < nch; ++c) {
        int sz = total - 12 * c; if (sz > 12) sz = 12;
        T.t[n] = (unsigned short)(qx | (c << 5) | (p << 8) | ((cum + c) << 9));
        sizes[n] = sz;
        ++n;
      }
    }
  for (int i = 1; i < n; ++i) {  // stable insertion sort, size desc
    unsigned short tv = T.t[i]; int sv = sizes[i];
    int j = i - 1;
    while (j >= 0 && sizes[j] < sv) { T.t[j + 1] = T.t[j]; sizes[j + 1] = sizes[j]; --j; }
    T.t[j + 1] = tv; sizes[j + 1] = sv;
  }
  return T;
}
__device__ __constant__ Tbl g_tbl = build_tbl();

// ---------------- causal flash attention, split-KV chunks, fixed-base softmax ----------------
// K depth-2 prefetch (3 slots) + V depth-1 (2 slots) = 40KB LDS -> 4 blocks/CU.
__device__ inline unsigned cvtpk(float lo, float hi_) {
  unsigned r;
  asm("v_cvt_pk_bf16_f32 %0, %1, %2" : "=v"(r) : "v"(lo), "v"(hi_));
  return r;
}

__global__ __launch_bounds__(256, 4) void attn_k(const __bf16* __restrict__ qkv,
                                                 const __bf16* __restrict__ vt,
                                                 __bf16* __restrict__ opart,
                                                 float* __restrict__ lpart,
                                                 __bf16* __restrict__ y) {
  __shared__ __bf16 k_lds[3][64 * 64];  // 24 KB
  __shared__ __bf16 v_lds[2][64 * 64];  // 16 KB
  const int tid = threadIdx.x, lane = tid & 63, w = tid >> 6;
  const int hi = lane >> 5, q31 = lane & 31;
  const int swz = q31 & 7;

  const int bid = (int)blockIdx.x;  // 1632
  const int e = g_tbl.t[bid >> 3];
  const int qx = e & 31, c = (e >> 5) & 7, p = (e >> 8) & 1, j = e >> 9;
  const int bh = (bid & 7) * 2 + p;  // XCD-local heads
  const int pslot = bh * 102 + j;
  const int b = bh >> 3, h = bh & 7;
  const int q0 = qx * 128;
  const int qw0 = q0 + w * 32;
  const int t0 = 12 * c;
  const int t1 = min(12 * c + 12, 2 * qx + 2);  // always >= 2 tiles

  const __bf16* qp = qkv + (size_t)b * 4096 * 1536 + h * 64;
  const __bf16* vtp = vt + (size_t)(b * 512 + h * 64) * 4096;

  // per-lane incremental stage pointers (involution XOR pre-applied to source)
  const int rr = tid >> 3;               // row within half-tile (0..31)
  const int cs = (tid & 7) ^ (rr & 7);   // (rr+32)&7 == rr&7, so same XOR both halves
  const __bf16* kg = qp + 512 + (size_t)(t0 * 64 + rr) * 1536 + cs * 8;
  const __bf16* vg = vtp + (size_t)rr * 4096 + t0 * 64 + cs * 8;

  bf16x8 qf[4];
  {
    const __bf16* qr = qp + (size_t)(qw0 + q31) * 1536 + hi * 8;
#pragma unroll
    for (int d = 0; d < 4; ++d) qf[d] = *reinterpret_cast<const bf16x8*>(qr + d * 16);
  }

  f32x16 o0 = {}, o1 = {};
  float l_run = 0.f;

  auto stageK = [&](int ks) {  // 2 loads/thread
    __builtin_amdgcn_global_load_lds((const AS1 void*)kg,
        (AS3 void*)(&k_lds[ks][w * 512]), 16, 0, 0);
    __builtin_amdgcn_global_load_lds((const AS1 void*)(kg + 32 * 1536),
        (AS3 void*)(&k_lds[ks][2048 + w * 512]), 16, 0, 0);
    kg += 64 * 1536;
  };
  auto stageV = [&](int vs) {  // 2 loads/thread
    __builtin_amdgcn_global_load_lds((const AS1 void*)vg,
        (AS3 void*)(&v_lds[vs][w * 512]), 16, 0, 0);
    __builtin_amdgcn_global_load_lds((const AS1 void*)(vg + 32 * 4096),
        (AS3 void*)(&v_lds[vs][2048 + w * 512]), 16, 0, 0);
    vg += 64;
  };

  // prologue
  stageV(0);
  __builtin_amdgcn_sched_barrier(0);
  stageK(0);
  __builtin_amdgcn_sched_barrier(0);
  stageK(1);
  __builtin_amdgcn_sched_barrier(0);

  int kslot = 0, vslot = 0;
  for (int t = t0; t < t1; ++t) {
    if (t + 1 < t1) asm volatile("s_waitcnt vmcnt(2)" ::: "memory");
    else            asm volatile("s_waitcnt vmcnt(0)" ::: "memory");
    __builtin_amdgcn_sched_barrier(0);
    __builtin_amdgcn_s_barrier();  // all waves' tile-t data landed
    __builtin_amdgcn_sched_barrier(0);
    if (t + 1 < t1) {
      stageV(vslot ^ 1);           // V depth-1
      __builtin_amdgcn_sched_barrier(0);
      if (t + 2 < t1) {
        int k2 = kslot + 2; if (k2 >= 3) k2 -= 3;
        stageK(k2);                // K depth-2
        __builtin_amdgcn_sched_barrier(0);
      }
    }
    const int kv0 = t * 64;
    if (kv0 <= qw0 + 31) {
      // S^T = K . Q^T
      f32x16 s0 = {}, s1 = {};
      __builtin_amdgcn_s_setprio(1);
#pragma unroll
      for (int d = 0; d < 4; ++d) {
        int c0 = ((d * 2 + hi) ^ swz) * 8;
        s0 = __builtin_amdgcn_mfma_f32_32x32x16_bf16(
            *reinterpret_cast<const bf16x8*>(&k_lds[kslot][q31 * 64 + c0]), qf[d], s0, 0, 0, 0);
        s1 = __builtin_amdgcn_mfma_f32_32x32x16_bf16(
            *reinterpret_cast<const bf16x8*>(&k_lds[kslot][(32 + q31) * 64 + c0]), qf[d], s1, 0, 0, 0);
      }
      __builtin_amdgcn_s_setprio(0);
      if (kv0 + 63 > qw0) {  // diagonal tile for this wave
        const int q = qw0 + q31;
#pragma unroll
        for (int r = 0; r < 16; ++r) {
          int crow = (r & 3) + 8 * (r >> 2) + 4 * hi;
          if (kv0 + crow > q) s0[r] = -1e30f;
          if (kv0 + 32 + crow > q) s1[r] = -1e30f;
        }
      }
      // fixed-base softmax: p = exp2(s); base shift cancels in O/l
#pragma unroll
      for (int r = 0; r < 16; ++r) s0[r] = EXP2(s0[r]);
#pragma unroll
      for (int r = 0; r < 16; ++r) s1[r] = EXP2(s1[r]);
      // lane-local tree sum (cross-lane merge deferred to chunk end)
      {
        float a8[8];
#pragma unroll
        for (int r = 0; r < 8; ++r)
          a8[r] = (s0[r] + s0[r + 8]) + (s1[r] + s1[r + 8]);
        l_run += (((a8[0] + a8[1]) + (a8[2] + a8[3])) + ((a8[4] + a8[5]) + (a8[6] + a8[7])));
      }
      // P fragments: cvt_pk + permlane32_swap
      uint32x4 pa[4];
#pragma unroll
      for (int half = 0; half < 2; ++half) {
        const int bse = half * 8;
        {
          unsigned x1 = cvtpk(s0[bse + 0], s0[bse + 1]);
          unsigned y1 = cvtpk(s0[bse + 4], s0[bse + 5]);
          asm("v_permlane32_swap_b32 %0, %1" : "+v"(x1), "+v"(y1));
          pa[half][0] = x1; pa[half][2] = y1;
          unsigned x2 = cvtpk(s0[bse + 2], s0[bse + 3]);
          unsigned y2 = cvtpk(s0[bse + 6], s0[bse + 7]);
          asm("v_permlane32_swap_b32 %0, %1" : "+v"(x2), "+v"(y2));
          pa[half][1] = x2; pa[half][3] = y2;
        }
        {
          unsigned x1 = cvtpk(s1[bse + 0], s1[bse + 1]);
          unsigned y1 = cvtpk(s1[bse + 4], s1[bse + 5]);
          asm("v_permlane32_swap_b32 %0, %1" : "+v"(x1), "+v"(y1));
          pa[2 + half][0] = x1; pa[2 + half][2] = y1;
          unsigned x2 = cvtpk(s1[bse + 2], s1[bse + 3]);
          unsigned y2 = cvtpk(s1[bse + 6], s1[bse + 7]);
          asm("v_permlane32_swap_b32 %0, %1" : "+v"(x2), "+v"(y2));
          pa[2 + half][1] = x2; pa[2 + half][3] = y2;
        }
      }
      // O^T += V^T . P^T
      __builtin_amdgcn_s_setprio(1);
#pragma unroll
      for (int ks = 0; ks < 4; ++ks) {
        int c0 = ((ks * 2 + hi) ^ swz) * 8;
        bf16x8 pfrag = __builtin_bit_cast(bf16x8, pa[ks]);
        o0 = __builtin_amdgcn_mfma_f32_32x32x16_bf16(
            *reinterpret_cast<const bf16x8*>(&v_lds[vslot][q31 * 64 + c0]), pfrag, o0, 0, 0, 0);
        o1 = __builtin_amdgcn_mfma_f32_32x32x16_bf16(
            *reinterpret_cast<const bf16x8*>(&v_lds[vslot][(32 + q31) * 64 + c0]), pfrag, o1, 0, 0, 0);
      }
      __builtin_amdgcn_s_setprio(0);
    }
    __builtin_amdgcn_sched_barrier(0);
    kslot = (kslot == 2) ? 0 : kslot + 1;
    vslot ^= 1;
  }

  // merge lane halves once per chunk
  l_run += __shfl_xor(l_run, 32);

  // epilogue
  const int rloc = w * 32 + q31;
  if (t0 == 0 && t1 == 2 * qx + 2) {
    // single-chunk q-block: write normalized y directly, skip combine
    const float inv = 1.f / l_run;
    __bf16* yr = y + ((size_t)b * 4096 + qw0 + q31) * 512 + h * 64;
#pragma unroll
    for (int g = 0; g < 4; ++g) {
      bf16x4 v0, v1;
#pragma unroll
      for (int jj = 0; jj < 4; ++jj) {
        v0[jj] = (__bf16)(o0[g * 4 + jj] * inv);
        v1[jj] = (__bf16)(o1[g * 4 + jj] * inv);
      }
      *reinterpret_cast<bf16x4*>(yr + 8 * g + 4 * hi) = v0;
      *reinterpret_cast<bf16x4*>(yr + 32 + 8 * g + 4 * hi) = v1;
    }
  } else {
    // multi-chunk: store RAW partial (shared fixed base) + l; combine sums plainly
    __bf16* ob = opart + ((size_t)pslot * 128 + rloc) * 64;
#pragma unroll
    for (int g = 0; g < 4; ++g) {
      bf16x4 v0, v1;
#pragma unroll
      for (int jj = 0; jj < 4; ++jj) {
        v0[jj] = (__bf16)(o0[g * 4 + jj]);
        v1[jj] = (__bf16)(o1[g * 4 + jj]);
      }
      *reinterpret_cast<bf16x4*>(ob + 8 * g + 4 * hi) = v0;
      *reinterpret_cast<bf16x4*>(ob + 32 + 8 * g + 4 * hi) = v1;
    }
    if (hi == 0) lpart[pslot * 128 + rloc] = l_run;
  }
}

// ---------------- combine partials -> y (bf16): y = (sum O_i) / (sum l_i) ----------------
// Compact 416-block grid (only multi-chunk q-blocks). XCD-aligned with attn's writer.
__global__ __launch_bounds__(256) void combine_k(const __bf16* __restrict__ opart,
                                                 const float* __restrict__ lpart,
                                                 __bf16* __restrict__ y) {
  const int bid = (int)blockIdx.x;  // 416 = 8 xcd * 52
  const int xcd = bid & 7, idx = bid >> 3;  // idx 0..51
  const int p = (idx >= 26) ? 1 : 0;
  const int bh = xcd * 2 + p;               // same bh<->XCD mapping as attn_k
  const int qx = 6 + (idx - 26 * p);        // 6..31
  const int b = bh >> 3, h = bh & 7;
  const int n = (2 * qx + 13) / 12;
  int cum = 0;
  for (int q = 0; q < qx; ++q) cum += (2 * q + 13) / 12;
  const int g0 = bh * 102 + cum;
  const int tid = threadIdx.x;
  const int r = tid >> 1, dh = (tid & 1) * 32;

  float W = 0.f;
  float acc[32] = {};
  for (int i = 0; i < n; ++i) {
    W += lpart[(g0 + i) * 128 + r];
    const __bf16* op = opart + ((size_t)(g0 + i) * 128 + r) * 64 + dh;
#pragma unroll
    for (int jj = 0; jj < 4; ++jj) {
      bf16x8 v = *reinterpret_cast<const bf16x8*>(op + jj * 8);
#pragma unroll
      for (int e = 0; e < 8; ++e) acc[jj * 8 + e] += (float)v[e];
    }
  }
  const float inv = 1.f / W;
  __bf16* yr = y + ((size_t)b * 4096 + qx * 128 + r) * 512 + h * 64 + dh;
#pragma unroll
  for (int jj = 0; jj < 4; ++jj) {
    bf16x8 ov;
#pragma unroll
    for (int e = 0; e < 8; ++e) ov[e] = (__bf16)(acc[jj * 8 + e] * inv);
    *reinterpret_cast<bf16x8*>(yr + jj * 8) = ov;
  }
}

// ---------------- launcher ----------------
extern "C" void kernel_launch(void* const* d_in, const int* in_sizes, int n_in,
                              void* d_out, int out_size, void* d_ws, size_t ws_size,
                              hipStream_t stream) {
  const float* x      = (const float*)d_in[0];
  const float* w_attn = (const float*)d_in[1];
  const float* b_attn = (const float*)d_in[2];
  const float* w_proj = (const float*)d_in[3];
  const float* b_proj = (const float*)d_in[4];
  float* out = (float*)d_out;

  const int Bv = 2, T = 4096, C = 512;
  const int M = Bv * T;  // 8192

  // ws layout (elements); opart aliases x_bf (x dead after gemm1, stream-ordered)
  const size_t NPART = (size_t)1632 * 128 * 64;
  __bf16* opart  = (__bf16*)d_ws;
  __bf16* x_bf   = opart;                            // 4,194,304 (subset)
  __bf16* wa_bf  = opart + NPART;                    // 786,432
  __bf16* wp_bf  = wa_bf + (size_t)786432;           // 262,144
  __bf16* qkv_bf = wp_bf + (size_t)262144;           // 12,582,912
  __bf16* y_bf   = qkv_bf + (size_t)12582912;        // 4,194,304
  __bf16* vt_bf  = y_bf + (size_t)4194304;           // 4,194,304
  float*  lpart  = (float*)(vt_bf + (size_t)4194304);  // 208,896 f32

  const int ntot = N_X + N_WA + N_WP;
  convert_all_k<<<(ntot / 8 + 255) / 256, 256, 0, stream>>>(x, w_attn, w_proj, x_bf, wa_bf, wp_bf);

  gemm_bt<<<dim3((3 * C / 128) * (M / 128)), 256, 0, stream>>>(x_bf, wa_bf, b_attn, qkv_bf, vt_bf, M, 3 * C, C);
  attn_k<<<dim3(1632), 256, 0, stream>>>(qkv_bf, vt_bf, opart, lpart, y_bf);
  combine_k<<<dim3(416), 256, 0, stream>>>(opart, lpart, y_bf);
  gemm2_k<<<dim3(1024), 256, 0, stream>>>(y_bf, wp_bf, b_proj, out);
}